// Round 1
// baseline (514.604 us; speedup 1.0000x reference)
//
#include <hip/hip_runtime.h>
#include <math.h>

#define N_CELLS 8192
#define HIDDIM 128
#define IN_DIM 64
#define TOPK 8

// ws layout (floats):
//     0 : dists[8192]
//  8192 : fpart[128*128]   (per-block faction-column partial sums, written
//                           unconditionally -> no zeroing kernel needed)

// K1: fused signal GEMV + per-cell distance + per-block proto column sums.
// One wave per cell: lane l owns dims 2l,2l+1 (float2, coalesced 512B/row).
// Each block covers 64 contiguous cells (64 | 1024 so one faction per block).
// Signal is recomputed per block in LDS (128x64 GEMV = 8K FLOP, negligible).
__global__ __launch_bounds__(256) void k_dist(const float* __restrict__ x,
                                              const float* __restrict__ in_w,
                                              const float* __restrict__ in_b,
                                              const float* __restrict__ proto,
                                              float* __restrict__ dists,
                                              float* __restrict__ fpart) {
    __shared__ float sig[HIDDIM];
    __shared__ float sm[4 * 128];
    int tid = threadIdx.x;
    if (tid < HIDDIM) {
        float acc = in_b[tid];
        const float* w = in_w + tid * IN_DIM;
        #pragma unroll
        for (int k = 0; k < IN_DIM; ++k) acc += x[k] * w[k];
        sig[tid] = acc;
    }
    __syncthreads();

    int wave = tid >> 6, lane = tid & 63;
    float sx = sig[2 * lane], sy = sig[2 * lane + 1];
    float fx = 0.0f, fy = 0.0f;
    int base = blockIdx.x * 64;
    for (int c = wave; c < 64; c += 4) {
        int cell = base + c;
        float2 p = ((const float2*)(proto + (size_t)cell * HIDDIM))[lane];
        float dx = p.x - sx, dy = p.y - sy;
        float d = dx * dx + dy * dy;
        #pragma unroll
        for (int off = 32; off > 0; off >>= 1) d += __shfl_down(d, off, 64);
        if (lane == 0) dists[cell] = d;
        fx += p.x; fy += p.y;
    }
    sm[wave * 128 + 2 * lane]     = fx;
    sm[wave * 128 + 2 * lane + 1] = fy;
    __syncthreads();
    if (tid < 128) {
        float s = sm[tid] + sm[128 + tid] + sm[256 + tid] + sm[384 + tid];
        fpart[blockIdx.x * 128 + tid] = s;   // plain store, no atomics
    }
}

// K2: fused top-8 + coef scan + epilogue. Single block, 256 threads.
// Phase A: stable top-8 (min dist, tie -> smaller index).
// Phase B: per-cell affine coefficient a_i; acoef kept in LDS (reuses sd);
//          sparse csum/Bf corrections via LDS atomics (~10 cells fire).
// Phase C: faction means from block partials, softmax weights, 8-row
//          reconstruction, expert MLPs + tension, output GEMV.
__global__ __launch_bounds__(256) void k_rest(const float* __restrict__ proto,
                                              const float* __restrict__ x,
                                              const float* __restrict__ in_w,
                                              const float* __restrict__ in_b,
                                              const float* __restrict__ dists,
                                              const float* __restrict__ fpart,
                                              const float* __restrict__ edges,
                                              const float* __restrict__ ages,
                                              const int* __restrict__ step_p,
                                              const float* __restrict__ ea_w1,
                                              const float* __restrict__ ea_b1,
                                              const float* __restrict__ ea_w2,
                                              const float* __restrict__ ea_b2,
                                              const float* __restrict__ eg_w1,
                                              const float* __restrict__ eg_b1,
                                              const float* __restrict__ eg_w2,
                                              const float* __restrict__ eg_b2,
                                              const float* __restrict__ out_w,
                                              const float* __restrict__ out_b,
                                              float* __restrict__ d_out) {
    __shared__ float sd[N_CELLS];       // 32 KB: dists, then reused as acoef
    __shared__ float sv[256];
    __shared__ int   si[256];
    __shared__ float topd_s[TOPK];
    __shared__ int   topi_s[TOPK];
    __shared__ float csum_s[8 * HIDDIM];
    __shared__ float Bf_s[8];
    __shared__ float wh[128], cmb[128], hA[128], hG[128];

    int tid = threadIdx.x;

    // zero the sparse-correction accumulators
    for (int j = tid; j < 8 * HIDDIM; j += 256) csum_s[j] = 0.0f;
    if (tid < 8) Bf_s[tid] = 0.0f;

    // ---- Phase A: load dists, stable top-8 ----
    for (int j = 0; j < 32; ++j) sd[j * 256 + tid] = dists[j * 256 + tid];
    __syncthreads();
    for (int k = 0; k < TOPK; ++k) {
        float lv = INFINITY; int li = N_CELLS;
        #pragma unroll
        for (int j = 0; j < 32; ++j) {
            int   ii = j * 256 + tid;
            float vv = sd[ii];
            if (vv < lv || (vv == lv && ii < li)) { lv = vv; li = ii; }
        }
        sv[tid] = lv; si[tid] = li;
        __syncthreads();
        for (int s = 128; s > 0; s >>= 1) {
            if (tid < s) {
                float ov = sv[tid + s]; int oi = si[tid + s];
                if (ov < sv[tid] || (ov == sv[tid] && oi < si[tid])) { sv[tid] = ov; si[tid] = oi; }
            }
            __syncthreads();
        }
        if (tid == 0) {
            topd_s[k] = sv[0];
            topi_s[k] = si[0];
            sd[si[0]] = INFINITY;    // exclude from later passes
        }
        __syncthreads();
    }

    // ---- Phase B: coef scan (sd becomes acoef) ----
    int bmu1 = topi_s[0], bmu2 = topi_s[1];
    float stepf = (float)step_p[0];
    float eps_w = fmaxf(0.05f, 0.3f * expf(-stepf / 200.0f));
    float eps_n = eps_w * 0.01f;
    for (int j = 0; j < 32; ++j) {
        int i = j * 256 + tid;
        size_t ro = (size_t)bmu1 * N_CELLS + (size_t)i;
        float age, ec;
        if (i == bmu2)      { age = 1.0f;             ec = 1.0f; }
        else if (i == bmu1) { age = ages[ro] + 2.0f;  ec = edges[ro]; }
        else                { age = ages[ro] + 1.0f;  ec = edges[ro]; }
        bool nb = ((age > 50.0f) ? 0.0f : ec) > 0.0f;
        float a = 1.0f;
        if (i == bmu1) a *= (1.0f - eps_w);
        if (i == bmu2) a *= (1.0f - eps_n);
        if (nb)        a *= (1.0f - eps_n);
        sd[i] = a;
        if (a != 1.0f) {
            int f = i >> 10;
            const float* p = proto + (size_t)i * HIDDIM;
            for (int d2 = 0; d2 < HIDDIM; ++d2)
                atomicAdd(&csum_s[f * HIDDIM + d2], (a - 1.0f) * p[d2]);
            atomicAdd(&Bf_s[f], 1.0f - a);
        }
    }
    __syncthreads();

    // ---- Phase C: epilogue ----
    int step = step_p[0];
    if (tid < 128) {
        int d = tid;
        // recompute signal dim d (128x64 GEMV row, trivial)
        float s = in_b[d];
        const float* w = in_w + d * IN_DIM;
        #pragma unroll
        for (int k = 0; k < IN_DIM; ++k) s += x[k] * w[k];

        // faction means (post-update p1) and global mean for dim d
        float fm[8]; float g = 0.0f;
        #pragma unroll
        for (int f = 0; f < 8; ++f) {
            float acc = csum_s[f * HIDDIM + d] + Bf_s[f] * s;
            for (int b = 0; b < 16; ++b) acc += fpart[(f * 16 + b) * 128 + d];
            float v = acc * (1.0f / 1024.0f);
            fm[f] = v; g += v;
        }
        g *= (1.0f / 8.0f);

        // softmax(-topdist); topd_s[0] is the min so -topd_s[0] is the max
        float wgt[TOPK]; float tot = 0.0f; float m = topd_s[0];
        #pragma unroll
        for (int k = 0; k < TOPK; ++k) { wgt[k] = expf(-(topd_s[k] - m)); tot += wgt[k]; }
        float inv = 1.0f / tot;

        float comb = 0.0f, win = 0.0f;
        #pragma unroll
        for (int k = 0; k < TOPK; ++k) {
            int idx = topi_s[k];
            float a  = sd[idx];                                   // acoef from LDS
            float p1 = a * proto[(size_t)idx * HIDDIM + d] + (1.0f - a) * s;
            float pf = 0.85f * p1 + 0.15f * fm[idx >> 10];        // faction sync
            if (step > 5 && (idx & 1023) < 256) pf = 0.85f * pf + 0.15f * g;  // debate
            comb += (wgt[k] * inv) * pf;
            if (k == 0) win = pf;                                 // winner_h = p_final[bmu1]
        }
        wh[d] = win; cmb[d] = comb;
    }
    __syncthreads();

    // expert hidden layers: waves 0-1 -> expert A, waves 2-3 -> expert G
    {
        int d = tid & 127;
        const float* w1 = (tid < 128) ? ea_w1 : eg_w1;
        const float* b1 = (tid < 128) ? ea_b1 : eg_b1;
        float h = b1[d];
        const float* wr = w1 + d * 128;
        for (int j = 0; j < 128; ++j) h += wh[j] * wr[j];
        if (tid < 128) hA[d] = fmaxf(h, 0.0f);
        else           hG[d] = fmaxf(h, 0.0f);
    }
    __syncthreads();

    if (tid < 64) {
        int d = tid;
        float ao = ea_b2[d], go = eg_b2[d], ov = out_b[d];
        for (int j = 0; j < 128; ++j) {
            ao += hA[j] * ea_w2[d * 128 + j];
            go += hG[j] * eg_w2[d * 128 + j];
            ov += cmb[j] * out_w[d * 128 + j];
        }
        d_out[d] = ov;
        float diff = ao - go;
        float sq = diff * diff;
        #pragma unroll
        for (int off = 32; off > 0; off >>= 1) sq += __shfl_down(sq, off, 64);
        if (d == 0) d_out[64] = sq * (1.0f / 64.0f);
    }
}

extern "C" void kernel_launch(void* const* d_in, const int* in_sizes, int n_in,
                              void* d_out, int out_size, void* d_ws, size_t ws_size,
                              hipStream_t stream) {
    (void)in_sizes; (void)n_in; (void)out_size; (void)ws_size;
    const float* x      = (const float*)d_in[0];
    const int*   step_p = (const int*)  d_in[1];
    const float* proto  = (const float*)d_in[2];
    const float* edges  = (const float*)d_in[3];
    const float* ages   = (const float*)d_in[4];
    const float* in_w   = (const float*)d_in[5];
    const float* in_b   = (const float*)d_in[6];
    const float* out_w  = (const float*)d_in[7];
    const float* out_b  = (const float*)d_in[8];
    const float* ea_w1  = (const float*)d_in[9];
    const float* ea_b1  = (const float*)d_in[10];
    const float* ea_w2  = (const float*)d_in[11];
    const float* ea_b2  = (const float*)d_in[12];
    const float* eg_w1  = (const float*)d_in[13];
    const float* eg_b1  = (const float*)d_in[14];
    const float* eg_w2  = (const float*)d_in[15];
    const float* eg_b2  = (const float*)d_in[16];

    float* ws    = (float*)d_ws;
    float* dists = ws;
    float* fpart = ws + N_CELLS;
    float* out   = (float*)d_out;

    k_dist<<<dim3(128), dim3(256), 0, stream>>>(x, in_w, in_b, proto, dists, fpart);
    k_rest<<<dim3(1),   dim3(256), 0, stream>>>(proto, x, in_w, in_b, dists, fpart,
                                                edges, ages, step_p,
                                                ea_w1, ea_b1, ea_w2, ea_b2,
                                                eg_w1, eg_b1, eg_w2, eg_b2,
                                                out_w, out_b, out);
}

// Round 2
// 485.277 us; speedup vs baseline: 1.0604x; 1.0604x over previous
//
#include <hip/hip_runtime.h>
#include <math.h>

#define N_CELLS 8192
#define HIDDIM 128
#define IN_DIM 64
#define TOPK 8

// ws layout (floats):
//     0 : dists[8192]
//  8192 : acoef[8192]
// 16384 : fpart[128*128]  (per-block faction-column partials, plain stores)
// 32768 : csum[1024]      \ zeroed contiguously (1032 floats)
// 33792 : Bf[8]           /
// 33800 : topdist[8]
// 33808 : topidx[8] (int)

__global__ void k_init(float* __restrict__ z) {
    int t = blockIdx.x * blockDim.x + threadIdx.x;
    if (t < 1032) z[t] = 0.0f;
}

// Fused signal GEMV + per-cell distance + per-block proto column sums.
// One wave per cell: lane l owns dims 2l,2l+1 (float2, coalesced 512B/row).
// Block covers 64 contiguous cells; 64 | 1024 so one faction per block
// (16 blocks/faction). Signal recomputed per block (8K FLOP, free).
__global__ __launch_bounds__(256) void k_dist(const float* __restrict__ x,
                                              const float* __restrict__ in_w,
                                              const float* __restrict__ in_b,
                                              const float* __restrict__ proto,
                                              float* __restrict__ dists,
                                              float* __restrict__ fpart) {
    __shared__ float sig[HIDDIM];
    __shared__ float sm[4 * 128];
    int tid = threadIdx.x;
    if (tid < HIDDIM) {
        float acc = in_b[tid];
        const float* w = in_w + tid * IN_DIM;
        #pragma unroll
        for (int k = 0; k < IN_DIM; ++k) acc += x[k] * w[k];
        sig[tid] = acc;
    }
    __syncthreads();

    int wave = tid >> 6, lane = tid & 63;
    float sx = sig[2 * lane], sy = sig[2 * lane + 1];
    float fx = 0.0f, fy = 0.0f;
    int base = blockIdx.x * 64;
    for (int c = wave; c < 64; c += 4) {
        int cell = base + c;
        float2 p = ((const float2*)(proto + (size_t)cell * HIDDIM))[lane];
        float dx = p.x - sx, dy = p.y - sy;
        float d = dx * dx + dy * dy;
        #pragma unroll
        for (int off = 32; off > 0; off >>= 1) d += __shfl_down(d, off, 64);
        if (lane == 0) dists[cell] = d;
        fx += p.x; fy += p.y;
    }
    sm[wave * 128 + 2 * lane]     = fx;
    sm[wave * 128 + 2 * lane + 1] = fy;
    __syncthreads();
    if (tid < 128) {
        float s = sm[tid] + sm[128 + tid] + sm[256 + tid] + sm[384 + tid];
        fpart[blockIdx.x * 128 + tid] = s;   // plain store, no atomics
    }
}

// Stable top-8 (min dist, tie -> smaller index), matching stable argsort.
// Thread tid owns cells {j*256+tid}; LDS layout j*256+tid is conflict-free.
__global__ __launch_bounds__(256) void k_top8(const float* __restrict__ dists,
                                              float* __restrict__ topdist,
                                              int* __restrict__ topidx) {
    __shared__ float sd[N_CELLS];   // 32 KB
    __shared__ float sv[256];
    __shared__ int   si[256];
    int tid = threadIdx.x;
    for (int j = 0; j < 32; ++j) sd[j * 256 + tid] = dists[j * 256 + tid];
    __syncthreads();
    for (int k = 0; k < TOPK; ++k) {
        float lv = INFINITY; int li = N_CELLS;
        #pragma unroll
        for (int j = 0; j < 32; ++j) {
            int   ii = j * 256 + tid;
            float vv = sd[ii];
            if (vv < lv || (vv == lv && ii < li)) { lv = vv; li = ii; }
        }
        sv[tid] = lv; si[tid] = li;
        __syncthreads();
        for (int s = 128; s > 0; s >>= 1) {
            if (tid < s) {
                float ov = sv[tid + s]; int oi = si[tid + s];
                if (ov < sv[tid] || (ov == sv[tid] && oi < si[tid])) { sv[tid] = ov; si[tid] = oi; }
            }
            __syncthreads();
        }
        if (tid == 0) {
            topdist[k] = sv[0];
            topidx[k]  = si[0];
            sd[si[0]]  = INFINITY;   // exclude from later passes
        }
        __syncthreads();
    }
}

// Per-cell affine coefficient a_i, plus sparse faction-sum corrections.
// Only needs ROW bmu1 of edges/edge_ages (the 256MB arrays are otherwise dead).
// 32 blocks x 256 threads: parallel, latency-hidden row scan.
__global__ __launch_bounds__(256) void k_coef(const float* __restrict__ proto,
                                              const float* __restrict__ edges,
                                              const float* __restrict__ ages,
                                              const int* __restrict__ step_p,
                                              const int* __restrict__ topidx,
                                              float* __restrict__ acoef,
                                              float* __restrict__ csum,
                                              float* __restrict__ Bf) {
    int i = blockIdx.x * blockDim.x + threadIdx.x;
    if (i >= N_CELLS) return;
    int bmu1 = topidx[0], bmu2 = topidx[1];
    float step = (float)step_p[0];
    float eps_w = fmaxf(0.05f, 0.3f * expf(-step / 200.0f));
    float eps_n = eps_w * 0.01f;

    size_t ro = (size_t)bmu1 * N_CELLS + (size_t)i;
    float age, ec;
    if (i == bmu2)      { age = 1.0f;             ec = 1.0f; }
    else if (i == bmu1) { age = ages[ro] + 2.0f;  ec = edges[ro]; }
    else                { age = ages[ro] + 1.0f;  ec = edges[ro]; }
    bool nb = ((age > 50.0f) ? 0.0f : ec) > 0.0f;

    float a = 1.0f;
    if (i == bmu1) a *= (1.0f - eps_w);
    if (i == bmu2) a *= (1.0f - eps_n);
    if (nb)        a *= (1.0f - eps_n);
    acoef[i] = a;

    if (a != 1.0f) {
        int f = i >> 10;
        const float* p = proto + (size_t)i * HIDDIM;
        for (int d = 0; d < HIDDIM; ++d)
            atomicAdd(&csum[f * HIDDIM + d], (a - 1.0f) * p[d]);
        atomicAdd(&Bf[f], 1.0f - a);
    }
}

// Epilogue: faction means (from block partials + sparse corrections), softmax
// weights, 8-row reconstruction, the two expert MLPs + tension, output GEMV.
__global__ __launch_bounds__(128) void k_final(const float* __restrict__ proto,
                                               const float* __restrict__ x,
                                               const float* __restrict__ in_w,
                                               const float* __restrict__ in_b,
                                               const float* __restrict__ acoef,
                                               const float* __restrict__ fpart,
                                               const float* __restrict__ csum,
                                               const float* __restrict__ Bf,
                                               const float* __restrict__ topdist,
                                               const int* __restrict__ topidx,
                                               const int* __restrict__ step_p,
                                               const float* __restrict__ ea_w1,
                                               const float* __restrict__ ea_b1,
                                               const float* __restrict__ ea_w2,
                                               const float* __restrict__ ea_b2,
                                               const float* __restrict__ eg_w1,
                                               const float* __restrict__ eg_b1,
                                               const float* __restrict__ eg_w2,
                                               const float* __restrict__ eg_b2,
                                               const float* __restrict__ out_w,
                                               const float* __restrict__ out_b,
                                               float* __restrict__ d_out) {
    __shared__ float wh[128], cmb[128], hA[128], hG[128];
    int d = threadIdx.x;  // 0..127, one dim per thread
    int step = step_p[0];

    // recompute signal dim d (one 64-wide dot, trivial)
    float s = in_b[d];
    {
        const float* w = in_w + d * IN_DIM;
        #pragma unroll
        for (int k = 0; k < IN_DIM; ++k) s += x[k] * w[k];
    }

    // faction means (post-update p1) and global mean for dim d
    float fm[8]; float g = 0.0f;
    #pragma unroll
    for (int f = 0; f < 8; ++f) {
        float acc = csum[f * HIDDIM + d] + Bf[f] * s;
        for (int b = 0; b < 16; ++b) acc += fpart[(f * 16 + b) * 128 + d];
        float v = acc * (1.0f / 1024.0f);
        fm[f] = v; g += v;
    }
    g *= (1.0f / 8.0f);

    // softmax(-topdist); topdist[0] is the min so -topdist[0] is the max
    float w[TOPK]; float tot = 0.0f; float m = topdist[0];
    #pragma unroll
    for (int k = 0; k < TOPK; ++k) { w[k] = expf(-(topdist[k] - m)); tot += w[k]; }
    float inv = 1.0f / tot;

    float comb = 0.0f, win = 0.0f;
    #pragma unroll
    for (int k = 0; k < TOPK; ++k) {
        int idx = topidx[k];
        float a  = acoef[idx];
        float p1 = a * proto[(size_t)idx * 128 + d] + (1.0f - a) * s;
        float pf = 0.85f * p1 + 0.15f * fm[idx >> 10];                 // faction sync
        if (step > 5 && (idx & 1023) < 256) pf = 0.85f * pf + 0.15f * g; // debate
        comb += (w[k] * inv) * pf;
        if (k == 0) win = pf;   // winner_h = p_final[bmu1]
    }
    wh[d] = win; cmb[d] = comb;
    __syncthreads();

    // expert hidden layers (128x128 each)
    float ha = ea_b1[d], hg = eg_b1[d];
    for (int j = 0; j < 128; ++j) {
        ha += wh[j] * ea_w1[d * 128 + j];
        hg += wh[j] * eg_w1[d * 128 + j];
    }
    hA[d] = fmaxf(ha, 0.0f);
    hG[d] = fmaxf(hg, 0.0f);
    __syncthreads();

    if (d < 64) {
        float ao = ea_b2[d], go = eg_b2[d], ov = out_b[d];
        for (int j = 0; j < 128; ++j) {
            ao += hA[j] * ea_w2[d * 128 + j];
            go += hG[j] * eg_w2[d * 128 + j];
            ov += cmb[j] * out_w[d * 128 + j];
        }
        d_out[d] = ov;
        float diff = ao - go;
        float sq = diff * diff;
        #pragma unroll
        for (int off = 32; off > 0; off >>= 1) sq += __shfl_down(sq, off, 64);
        if (d == 0) d_out[64] = sq * (1.0f / 64.0f);
    }
}

extern "C" void kernel_launch(void* const* d_in, const int* in_sizes, int n_in,
                              void* d_out, int out_size, void* d_ws, size_t ws_size,
                              hipStream_t stream) {
    (void)in_sizes; (void)n_in; (void)out_size; (void)ws_size;
    const float* x      = (const float*)d_in[0];
    const int*   step_p = (const int*)  d_in[1];
    const float* proto  = (const float*)d_in[2];
    const float* edges  = (const float*)d_in[3];
    const float* ages   = (const float*)d_in[4];
    const float* in_w   = (const float*)d_in[5];
    const float* in_b   = (const float*)d_in[6];
    const float* out_w  = (const float*)d_in[7];
    const float* out_b  = (const float*)d_in[8];
    const float* ea_w1  = (const float*)d_in[9];
    const float* ea_b1  = (const float*)d_in[10];
    const float* ea_w2  = (const float*)d_in[11];
    const float* ea_b2  = (const float*)d_in[12];
    const float* eg_w1  = (const float*)d_in[13];
    const float* eg_b1  = (const float*)d_in[14];
    const float* eg_w2  = (const float*)d_in[15];
    const float* eg_b2  = (const float*)d_in[16];

    float* ws    = (float*)d_ws;
    float* dists = ws;
    float* acoef = ws + 8192;
    float* fpart = ws + 16384;
    float* csum  = ws + 32768;
    float* Bf    = ws + 33792;
    float* topd  = ws + 33800;
    int*   topi  = (int*)(ws + 33808);
    float* out   = (float*)d_out;

    k_init <<<dim3(5),   dim3(256), 0, stream>>>(csum);   // zeros csum+Bf (1032 floats)
    k_dist <<<dim3(128), dim3(256), 0, stream>>>(x, in_w, in_b, proto, dists, fpart);
    k_top8 <<<dim3(1),   dim3(256), 0, stream>>>(dists, topd, topi);
    k_coef <<<dim3(32),  dim3(256), 0, stream>>>(proto, edges, ages, step_p, topi, acoef, csum, Bf);
    k_final<<<dim3(1),   dim3(128), 0, stream>>>(proto, x, in_w, in_b, acoef, fpart, csum, Bf, topd, topi, step_p,
                                                 ea_w1, ea_b1, ea_w2, ea_b2,
                                                 eg_w1, eg_b1, eg_w2, eg_b2,
                                                 out_w, out_b, out);
}